// Round 15
// baseline (216.244 us; speedup 1.0000x reference)
//
#include <hip/hip_runtime.h>

// RandHashProj: out[b, sel[r]] += sign[r] * x[b, r]
// proj (8192x8192 f32): exactly ONE +-1 per row; per-column count ~ Poisson(1).
// R15 = R14 extract + double-buffered pipelined gather with VGPR discipline:
//   512 blocks x 8 rows (4 groups of 2), 2x32 KiB bf16-packed LDS ping-pong,
//   __launch_bounds__(512,4) enforces <=128 VGPR -> 2 blocks/CU (R12 likely
//   failed by exceeding 128 -> 1 block/CU starvation, same as R10).
//   Loop: issue NT loads(g+1) -> compute(g) -> pack->other buf -> barrier.
//   Loads precede stores in program order -> compiler emits counted vmcnt.
// ELL entry (ushort): (r<<2)|(sign<<1)|1 ; EMPTY=0 -> weight 0 (reads xs[0]).
// Overflow (~35 entries) in a separate thread-owns-row kernel (no atomics).

#define OUT_FEAT 8192
#define IN_FEAT 8192

typedef float vfloat4 __attribute__((ext_vector_type(4)));

// ---- Kernel A: wave-per-row early-exit scan of proj (NT loads) ----
__global__ void __launch_bounds__(256) extract_fill(const vfloat4* __restrict__ proj4,
        int* __restrict__ cur, int* __restrict__ onum,
        unsigned int* __restrict__ ovals, unsigned short* __restrict__ ell) {
    int row = (blockIdx.x << 2) + (threadIdx.x >> 6);   // wave-per-row
    int lane = threadIdx.x & 63;
    const vfloat4* rp = proj4 + (size_t)row * (IN_FEAT / 4) + lane;

    vfloat4 v = __builtin_nontemporal_load(rp);         // chunk 0 (1 KiB/wave)
    #pragma unroll 1
    for (int k = 0; k < 32; ++k) {
        vfloat4 vn;
        if (k + 1 < 32) vn = __builtin_nontemporal_load(rp + (size_t)(k + 1) * 64);
        bool hit = (v.x != 0.f) || (v.y != 0.f) || (v.z != 0.f) || (v.w != 0.f);
        if (__ballot(hit)) {              // wave-uniform -> no divergence
            if (hit) {                    // exactly one lane, one component
                int comp; float a;
                if      (v.x != 0.f) { comp = 0; a = v.x; }
                else if (v.y != 0.f) { comp = 1; a = v.y; }
                else if (v.z != 0.f) { comp = 2; a = v.z; }
                else                 { comp = 3; a = v.w; }
                int c = (k << 8) + (lane << 2) + comp;    // column in row
                int sg = (a < 0.f) ? 1 : 0;
                int pos = atomicAdd(&cur[c], 1);
                if (pos < 4) {
                    ell[c * 4 + pos] = (unsigned short)((row << 2) | (sg << 1) | 1);
                } else {
                    int o = atomicAdd(onum, 1);
                    ovals[o] = ((unsigned int)c << 14) | ((unsigned int)row << 1) | sg;
                }
            }
            break;
        }
        v = vn;
    }
}

__device__ __forceinline__ unsigned int pack_bf16(float a, float b) {
    unsigned int ua = __builtin_bit_cast(unsigned int, a);
    unsigned int ub = __builtin_bit_cast(unsigned int, b);
    ua = (ua + 0x8000u) >> 16;
    ub = (ub + 0x8000u) & 0xFFFF0000u;
    return ub | ua;
}

// one ELL slot -> fma into s0/s1 (branchless; empty e=0 -> wt=0, reads buf[0])
#define SLOT(ek)                                                                 \
    {                                                                            \
        unsigned int _e = (ek);                                                  \
        unsigned int _u = *(const unsigned int*)(bufc + (_e & 0xFFFCu));         \
        float _wt = __builtin_bit_cast(float,                                    \
            ((0u - (_e & 1u)) & 0x3F800000u) | ((_e << 30) & 0x80000000u));      \
        s0 = fmaf(_wt, __builtin_bit_cast(float, _u << 16), s0);                 \
        s1 = fmaf(_wt, __builtin_bit_cast(float, _u & 0xFFFF0000u), s1);         \
    }

// one column (two packed slot-words) -> its two row sums
#define COL(u01, u23, dA, dB)                                                    \
    {                                                                            \
        float s0 = 0.f, s1 = 0.f;                                                \
        SLOT((u01) & 0xFFFFu);                                                   \
        SLOT((u01) >> 16);                                                       \
        SLOT((u23) & 0xFFFFu);                                                   \
        SLOT((u23) >> 16);                                                       \
        dA = s0; dB = s1;                                                        \
    }

// pack pf[0..7] (rows A,B interleaved as pf[i]=rowA grp i, pf[4+i]=rowB grp i)
#define PACK_TO(dstbuf)                                                          \
    {                                                                            \
        unsigned int* _xd = (unsigned int*)(dstbuf);                             \
        _Pragma("unroll")                                                        \
        for (int i = 0; i < 4; ++i) {                                            \
            int idx = (i << 9) | t;                                              \
            uint4 p;                                                             \
            p.x = pack_bf16(pf[i].x, pf[4 + i].x);                               \
            p.y = pack_bf16(pf[i].y, pf[4 + i].y);                               \
            p.z = pack_bf16(pf[i].z, pf[4 + i].z);                               \
            p.w = pack_bf16(pf[i].w, pf[4 + i].w);                               \
            ((uint4*)_xd)[idx] = p;                                              \
        }                                                                        \
    }

#define LOAD_GROUP(base)                                                         \
    {                                                                            \
        const vfloat4* _x0 = x4 + (size_t)(base) * (IN_FEAT / 4);                \
        const vfloat4* _x1 = _x0 + (IN_FEAT / 4);                                \
        _Pragma("unroll")                                                        \
        for (int i = 0; i < 4; ++i) {                                            \
            int idx = (i << 9) | t;                                              \
            pf[i]     = __builtin_nontemporal_load(_x0 + idx);                   \
            pf[4 + i] = __builtin_nontemporal_load(_x1 + idx);                   \
        }                                                                        \
    }

// ---- Kernel B: pipelined gather, 8 rows/block, 2x32 KiB ping-pong ----
__global__ void __launch_bounds__(512, 4) gather8_kernel(const vfloat4* __restrict__ x4,
        const unsigned short* __restrict__ ell, float* __restrict__ out) {
    __shared__ unsigned int xs[2][IN_FEAT];   // 2 x 32 KiB
    int t = threadIdx.x;
    int lane = t & 63;
    int wv = t >> 6;                 // 8 waves

    // ELL slice -> registers (32 VGPR).
    uint4 ea[4], eb[4];
    #pragma unroll
    for (int g = 0; g < 4; ++g) {
        int c0 = (wv << 10) + (g << 8) + (lane << 2);
        const uint4* p = (const uint4*)(ell + (size_t)c0 * 4);
        ea[g] = p[0];
        eb[g] = p[1];
    }

    int b0 = blockIdx.x * 8;
    vfloat4 pf[8];                   // 32 VGPR prefetch window

    // Prologue: stage group 0.
    LOAD_GROUP(b0);
    PACK_TO(xs[0]);
    __syncthreads();

    #pragma unroll
    for (int g = 0; g < 4; ++g) {
        // Issue next group's NT loads (oldest vmem ops; fly under compute).
        if (g < 3) LOAD_GROUP(b0 + 2 * (g + 1));

        // Compute group g from buf[g&1].
        const char* bufc = (const char*)xs[g & 1];
        float* orow0 = out + (size_t)(b0 + 2 * g) * OUT_FEAT;
        float* orow1 = orow0 + OUT_FEAT;
        #pragma unroll
        for (int cg = 0; cg < 4; ++cg) {
            int c0 = (wv << 10) + (cg << 8) + (lane << 2);
            float4 o0, o1;
            COL(ea[cg].x, ea[cg].y, o0.x, o1.x);
            COL(ea[cg].z, ea[cg].w, o0.y, o1.y);
            COL(eb[cg].x, eb[cg].y, o0.z, o1.z);
            COL(eb[cg].z, eb[cg].w, o0.w, o1.w);
            *(float4*)(orow0 + c0) = o0;   // wave stores 1 KiB contiguous
            *(float4*)(orow1 + c0) = o1;
        }

        // Pack prefetched rows into the other buffer (counted vmcnt lands here).
        if (g < 3) PACK_TO(xs[(g + 1) & 1]);
        __syncthreads();
    }
}

// ---- Kernel C: overflow (~35 entries). Thread owns one batch row: no atomics. ----
__global__ void overflow_kernel(const float* __restrict__ x,
        const unsigned int* __restrict__ ovals, const int* __restrict__ onum_p,
        float* __restrict__ out, int batch) {
    int b = blockIdx.x * blockDim.x + threadIdx.x;
    if (b >= batch) return;
    int on = *onum_p;
    const float* xrow = x + (size_t)b * IN_FEAT;
    float* orow = out + (size_t)b * OUT_FEAT;
    for (int m = 0; m < on; ++m) {
        unsigned int e = ovals[m];
        int c = (int)(e >> 14);
        int r = (int)((e >> 1) & (IN_FEAT - 1));
        float wt = (e & 1) ? -1.f : 1.f;
        orow[c] += wt * xrow[r];   // exclusive row ownership -> plain RMW
    }
}

extern "C" void kernel_launch(void* const* d_in, const int* in_sizes, int n_in,
                              void* d_out, int out_size, void* d_ws, size_t ws_size,
                              hipStream_t stream) {
    const float* x = (const float*)d_in[0];
    const float* proj = (const float*)d_in[1];
    float* out = (float*)d_out;

    const int out_feat = OUT_FEAT;
    long proj_elems = (long)in_sizes[1];
    int in_feat = (int)(proj_elems / out_feat);   // 8192
    int batch = in_sizes[0] / in_feat;            // 4096

    // ws layout: [cur 32 KiB][onum 4 B][pad 60 B][ell 64 KiB][ovals 32 KiB]
    // EMPTY ELL entry = 0 -> one memset covers cur+onum+ell.
    char* w = (char*)d_ws;
    int* cur = (int*)w;
    int* onum = (int*)(w + 32 * 1024);
    unsigned short* ell = (unsigned short*)(w + 32 * 1024 + 64);
    unsigned int* ovals = (unsigned int*)(w + 96 * 1024 + 64);

    (void)hipMemsetAsync(cur, 0, 96 * 1024 + 64, stream);
    extract_fill<<<IN_FEAT / 4, 256, 0, stream>>>((const vfloat4*)proj, cur, onum,
                                                  ovals, ell);
    gather8_kernel<<<batch / 8, 512, 0, stream>>>((const vfloat4*)x, ell, out);
    overflow_kernel<<<(batch + 255) / 256, 256, 0, stream>>>(x, ovals, onum, out, batch);
}

// Round 16
// 94.096 us; speedup vs baseline: 2.2981x; 2.2981x over previous
//
#include <hip/hip_runtime.h>

// RandHashProj: out[b, sel[r]] += sign[r] * x[b, r]
// proj (8192x8192 f32): exactly ONE +-1 per row; per-column count ~ Poisson(1).
// R16 = exact revert to R14 (best: 94.7 us). Pipelined variants R6/R10/R12/R15
// all regressed (spill / occupancy / vmcnt); this is the measured optimum.
//  - early-exit wave-per-row extract with NT proj loads
//  - width-4 ELL, entry (r<<2)|(sign<<1)|1, EMPTY=0 -> weight 0
//    => single memset initializes cur+onum+ell (no init kernel)
//  - gather2: 2 rows/block, bf16-pair LDS, ELL slice in registers,
//    4 consecutive cols/thread -> float4 stores; NT x loads; inline overflow.

#define OUT_FEAT 8192
#define IN_FEAT 8192

typedef float vfloat4 __attribute__((ext_vector_type(4)));

// ---- Kernel A: wave-per-row early-exit scan of proj ----
__global__ void __launch_bounds__(256) extract_fill(const vfloat4* __restrict__ proj4,
        int* __restrict__ cur, int* __restrict__ onum,
        unsigned int* __restrict__ ovals, unsigned short* __restrict__ ell) {
    int row = (blockIdx.x << 2) + (threadIdx.x >> 6);   // wave-per-row
    int lane = threadIdx.x & 63;
    const vfloat4* rp = proj4 + (size_t)row * (IN_FEAT / 4) + lane;

    vfloat4 v = __builtin_nontemporal_load(rp);         // chunk 0 (1 KiB/wave)
    #pragma unroll 1
    for (int k = 0; k < 32; ++k) {
        vfloat4 vn;
        if (k + 1 < 32) vn = __builtin_nontemporal_load(rp + (size_t)(k + 1) * 64);
        bool hit = (v.x != 0.f) || (v.y != 0.f) || (v.z != 0.f) || (v.w != 0.f);
        if (__ballot(hit)) {              // wave-uniform -> no divergence
            if (hit) {                    // exactly one lane, one component
                int comp; float a;
                if      (v.x != 0.f) { comp = 0; a = v.x; }
                else if (v.y != 0.f) { comp = 1; a = v.y; }
                else if (v.z != 0.f) { comp = 2; a = v.z; }
                else                 { comp = 3; a = v.w; }
                int c = (k << 8) + (lane << 2) + comp;    // column in row
                int sg = (a < 0.f) ? 1 : 0;
                int pos = atomicAdd(&cur[c], 1);
                if (pos < 4) {
                    ell[c * 4 + pos] = (unsigned short)((row << 2) | (sg << 1) | 1);
                } else {
                    int o = atomicAdd(onum, 1);
                    ovals[o] = ((unsigned int)c << 14) | ((unsigned int)row << 1) | sg;
                }
            }
            break;
        }
        v = vn;
    }
}

__device__ __forceinline__ unsigned int pack_bf16(float a, float b) {
    unsigned int ua = __builtin_bit_cast(unsigned int, a);
    unsigned int ub = __builtin_bit_cast(unsigned int, b);
    ua = (ua + 0x8000u) >> 16;
    ub = (ub + 0x8000u) & 0xFFFF0000u;
    return ub | ua;
}

// one ELL slot -> fma into s0/s1 (branchless; empty e=0 -> wt=0, reads xs[0])
#define SLOT(ek)                                                                 \
    {                                                                            \
        unsigned int _e = (ek);                                                  \
        unsigned int _u = *(const unsigned int*)(bufc + (_e & 0xFFFCu));         \
        float _wt = __builtin_bit_cast(float,                                    \
            ((0u - (_e & 1u)) & 0x3F800000u) | ((_e << 30) & 0x80000000u));      \
        s0 = fmaf(_wt, __builtin_bit_cast(float, _u << 16), s0);                 \
        s1 = fmaf(_wt, __builtin_bit_cast(float, _u & 0xFFFF0000u), s1);         \
    }

// one column (two packed slot-words) -> its two row sums
#define COL(u01, u23, dA, dB)                                                    \
    {                                                                            \
        float s0 = 0.f, s1 = 0.f;                                                \
        SLOT((u01) & 0xFFFFu);                                                   \
        SLOT((u01) >> 16);                                                       \
        SLOT((u23) & 0xFFFFu);                                                   \
        SLOT((u23) >> 16);                                                       \
        dA = s0; dB = s1;                                                        \
    }

// ---- Kernel B: gather, 2 rows/block, bf16-packed LDS, ELL in registers,
//      4 consecutive columns per thread -> float4 stores ----
__global__ void __launch_bounds__(512, 4) gather2_kernel(const vfloat4* __restrict__ x4,
        const unsigned short* __restrict__ ell, const unsigned int* __restrict__ ovals,
        const int* __restrict__ onum_p, float* __restrict__ out) {
    __shared__ unsigned int xs[IN_FEAT];
    int t = threadIdx.x;
    int lane = t & 63;
    int wv = t >> 6;                 // 8 waves

    // This thread's 4 column-groups (4 consecutive cols each) -> registers.
    uint4 ea[4], eb[4];
    #pragma unroll
    for (int g = 0; g < 4; ++g) {
        int c0 = (wv << 10) + (g << 8) + (lane << 2);
        const uint4* p = (const uint4*)(ell + (size_t)c0 * 4);
        ea[g] = p[0];                // cols c0, c0+1 (slots 01,23 each)
        eb[g] = p[1];                // cols c0+2, c0+3
    }

    int b0 = blockIdx.x * 2;
    const vfloat4* xr0 = x4 + (size_t)b0 * (IN_FEAT / 4);
    const vfloat4* xr1 = xr0 + (IN_FEAT / 4);
    #pragma unroll
    for (int i = 0; i < 4; ++i) {
        int idx = (i << 9) | t;
        vfloat4 a = __builtin_nontemporal_load(xr0 + idx);
        vfloat4 b = __builtin_nontemporal_load(xr1 + idx);
        uint4 p;
        p.x = pack_bf16(a.x, b.x);
        p.y = pack_bf16(a.y, b.y);
        p.z = pack_bf16(a.z, b.z);
        p.w = pack_bf16(a.w, b.w);
        ((uint4*)xs)[idx] = p;
    }
    __syncthreads();

    float* orow0 = out + (size_t)b0 * OUT_FEAT;
    float* orow1 = orow0 + OUT_FEAT;
    const char* bufc = (const char*)xs;

    #pragma unroll
    for (int g = 0; g < 4; ++g) {
        int c0 = (wv << 10) + (g << 8) + (lane << 2);
        float4 o0, o1;
        COL(ea[g].x, ea[g].y, o0.x, o1.x);
        COL(ea[g].z, ea[g].w, o0.y, o1.y);
        COL(eb[g].x, eb[g].y, o0.z, o1.z);
        COL(eb[g].z, eb[g].w, o0.w, o1.w);
        *(float4*)(orow0 + c0) = o0;   // wave stores 1 KiB contiguous
        *(float4*)(orow1 + c0) = o1;
    }

    // Overflow (~35 entries total). Barrier drains plain stores first.
    __syncthreads();
    int on = *onum_p;
    for (int m = t; m < on; m += 512) {
        unsigned int e = ovals[m];
        int c = (int)(e >> 14);
        int r = (int)((e >> 1) & (IN_FEAT - 1));
        float wt = (e & 1) ? -1.f : 1.f;
        unsigned int u = xs[r];
        atomicAdd(&orow0[c], wt * __builtin_bit_cast(float, u << 16));
        atomicAdd(&orow1[c], wt * __builtin_bit_cast(float, u & 0xFFFF0000u));
    }
}

extern "C" void kernel_launch(void* const* d_in, const int* in_sizes, int n_in,
                              void* d_out, int out_size, void* d_ws, size_t ws_size,
                              hipStream_t stream) {
    const float* x = (const float*)d_in[0];
    const float* proj = (const float*)d_in[1];
    float* out = (float*)d_out;

    const int out_feat = OUT_FEAT;
    long proj_elems = (long)in_sizes[1];
    int in_feat = (int)(proj_elems / out_feat);   // 8192
    int batch = in_sizes[0] / in_feat;            // 4096

    // ws layout: [cur 32 KiB][onum 4 B][pad 60 B][ell 64 KiB][ovals 32 KiB]
    // EMPTY ELL entry = 0 -> one memset covers cur+onum+ell.
    char* w = (char*)d_ws;
    int* cur = (int*)w;
    int* onum = (int*)(w + 32 * 1024);
    unsigned short* ell = (unsigned short*)(w + 32 * 1024 + 64);
    unsigned int* ovals = (unsigned int*)(w + 96 * 1024 + 64);

    (void)hipMemsetAsync(cur, 0, 96 * 1024 + 64, stream);
    extract_fill<<<IN_FEAT / 4, 256, 0, stream>>>((const vfloat4*)proj, cur, onum,
                                                  ovals, ell);
    gather2_kernel<<<batch / 2, 512, 0, stream>>>((const vfloat4*)x, ell, ovals,
                                                  onum, out);
}